// Round 14
// baseline (158.661 us; speedup 1.0000x reference)
//
#include <hip/hip_runtime.h>

// GCN 2-layer + linear head on MI355X.
// R13 post-mortem: agg-4-node + self-fold good (158->140), but the
// readfirstlane/s_load GEMM REGRESSED (46us replay, VALU 23%, 842GB/s --
// dependent s_load chains, no MLP on the scalar pipe). R14: revert GEMM to
// the readlane form (vector row load + 64x readlane+fmac, ~13us), keep
// everything else from R13.

typedef float v2f __attribute__((ext_vector_type(2)));

constexpr int NB_SHIFT = 8;                 // 256 nodes per bucket
constexpr int BUCK_NODES = 1 << NB_SHIFT;
constexpr int CAP = 5120;                   // slab cap (max bucket ~3500 + 512 self + pad)
constexpr int CHUNK = 4096;                 // edges per sort block
constexpr int STPB = 512;
// assumes nbuck <= 512, src < 2^17, padded bucket size <= CAP

// ---- init: slab cursors + dummy bf16 row (replaces hipMemsetAsync) -----
__global__ __launch_bounds__(512) void k_init(int* __restrict__ gcur, int nbuck,
                                              unsigned short* __restrict__ dummyRow) {
    int t = threadIdx.x;
    if (t < nbuck) gcur[t] = 0;
    if (t < 64) dummyRow[t] = 0;
}

// ---- fused: chunk histogram -> slab reserve -> LDS sort -> dense flush -
__global__ __launch_bounds__(STPB) void k_bsort(const int* __restrict__ src,
                                                const int* __restrict__ dst, int E, int nbuck,
                                                int* __restrict__ gcur,
                                                unsigned* __restrict__ packed) {
    __shared__ int shStart[512];
    __shared__ int shCur[512];
    __shared__ int shOff[512];
    __shared__ unsigned stage[CHUNK];
    __shared__ unsigned short sbkt[CHUNK];
    const int tid = threadIdx.x;
    const int base = blockIdx.x * CHUNK;
    const int end = min(base + CHUNK, E);
    // pass A: count buckets in this chunk (LDS atomics)
    shCur[tid] = 0;
    __syncthreads();
    for (int e = base + tid; e < end; e += STPB)
        atomicAdd(&shCur[dst[e] >> NB_SHIFT], 1);
    __syncthreads();
    int v = shCur[tid];
    shStart[tid] = v;
    __syncthreads();
    for (int s = 1; s < 512; s <<= 1) {      // inclusive Hillis-Steele
        int a = (tid >= s) ? shStart[tid - s] : 0;
        __syncthreads();
        shStart[tid] += a;
        __syncthreads();
    }
    int exc = shStart[tid] - v;
    shStart[tid] = exc;
    shCur[tid] = exc;
    // reserve this chunk's span in bucket slabs (one global atomic each)
    if (tid < nbuck) shOff[tid] = tid * CAP + ((v > 0) ? atomicAdd(&gcur[tid], v) : 0);
    __syncthreads();
    // pass B: permute chunk into LDS, bucket-major
    for (int e = base + tid; e < end; e += STPB) {
        int s = src[e];
        int d = dst[e];
        int b = d >> NB_SHIFT;
        int slot = atomicAdd(&shCur[b], 1);
        stage[slot] = ((unsigned)(d & (BUCK_NODES - 1)) << 17) | (unsigned)s;
        sbkt[slot] = (unsigned short)b;
    }
    __syncthreads();
    // pass C: linear flush, same-bucket runs land contiguously
    int cnt = end - base;
    for (int i = tid; i < cnt; i += STPB) {
        int b = sbkt[i];
        packed[shOff[b] + (i - shStart[b])] = stage[i];
    }
}

// ---- per-bucket counting sort by dstLocal -> csr slab; appends SELF edge
//      then pads to x2. rowinfo=(start, paddedCount), dinv ---------------
__global__ __launch_bounds__(512) void k_csr(const unsigned* __restrict__ packed,
                                             const int* __restrict__ gcur, int n,
                                             int* __restrict__ csr, int2* __restrict__ rowinfo,
                                             float* __restrict__ dinv) {
    __shared__ int cnt[BUCK_NODES];
    __shared__ int scn[BUCK_NODES];
    __shared__ int cur[BUCK_NODES];
    const int tid = threadIdx.x;
    const int e0 = blockIdx.x * CAP;
    const int e1 = e0 + gcur[blockIdx.x];     // slab base + size
    if (tid < BUCK_NODES) cnt[tid] = 0;
    __syncthreads();
    for (int e = e0 + tid; e < e1; e += 512)
        atomicAdd(&cnt[packed[e] >> 17], 1);
    __syncthreads();
    int v = (tid < BUCK_NODES) ? cnt[tid] : 0;
    int pad = (v + 2) & ~1;                   // v edges + 1 self, rounded to x2
    if (tid < BUCK_NODES) scn[tid] = pad;
    __syncthreads();
    for (int s = 1; s < BUCK_NODES; s <<= 1) {   // inclusive Hillis-Steele
        int add = (tid >= s && tid < BUCK_NODES) ? scn[tid - s] : 0;
        __syncthreads();
        if (tid < BUCK_NODES) scn[tid] += add;
        __syncthreads();
    }
    int start = 0;
    if (tid < BUCK_NODES) {
        start = e0 + scn[tid] - pad;
        cur[tid] = start;
        int node = blockIdx.x * BUCK_NODES + tid;
        if (node < n) {
            rowinfo[node] = make_int2(start, pad);
            dinv[node] = rsqrtf(1.0f + (float)v);
        }
    }
    __syncthreads();
    for (int e = e0 + tid; e < e1; e += 512) {
        unsigned p = packed[e];
        int pos = atomicAdd(&cur[p >> 17], 1);   // LDS cursor
        csr[pos] = (int)(p & 0x1FFFFu);          // dense slab window, L2-hot
    }
    __syncthreads();
    // append self edge, then dummy-pad (index n = zero bf16 row)
    if (tid < BUCK_NODES) {
        int node = blockIdx.x * BUCK_NODES + tid;
        csr[start + v] = (node < n) ? node : n;
        for (int p = v + 1; p < pad; ++p) csr[start + p] = n;
    }
}

// ---- GEMM: gBf[i][f] = bf16((sum_k A[i][k] * W[k][f]) * dinv[i]) -------
// One vector row load + 64x readlane+fmac per row (known-good ~13us).
__global__ __launch_bounds__(256) void k_gemm64bf(const float* __restrict__ A,
                                                  const float* __restrict__ W,
                                                  const float* __restrict__ dinv,
                                                  unsigned short* __restrict__ out,
                                                  int n) {
    const int lane = threadIdx.x & 63;
    const int wave = threadIdx.x >> 6;
    float wcol[64];
#pragma unroll
    for (int k = 0; k < 64; ++k) wcol[k] = W[k * 64 + lane];
    int base = blockIdx.x * 64;
    for (int r = wave; r < 64; r += 4) {
        int row = base + r;
        if (row >= n) break;
        float a = A[(size_t)row * 64 + lane];
        float acc = 0.0f;
#pragma unroll
        for (int k = 0; k < 64; ++k) {
            float ak = __uint_as_float(__builtin_amdgcn_readlane(__float_as_uint(a), k));
            acc = fmaf(ak, wcol[k], acc);
        }
        float val = acc * dinv[row];
        unsigned u = __float_as_uint(val);
        u = (u + 0x7FFFu + ((u >> 16) & 1u)) >> 16;   // RNE to bf16
        out[(size_t)row * 64 + lane] = (unsigned short)u;
    }
}

__device__ __forceinline__ v2f bf2(unsigned u) {
    v2f r;
    r.x = __uint_as_float(u << 16);
    r.y = __uint_as_float(u & 0xFFFF0000u);
    return r;
}

// ---- Aggregate: FOUR nodes per wave (16 lanes each); bf16 rows ---------
// lane = 16*s + 8*grp + q. Node slot s; grp in {0,1} handles edge e+2r+grp;
// q the 16B row chunk (features 8q..8q+7). Self-loop is already in csr.
// Reduce: 1 halving round (mask 8) -> each lane owns 4 features
// base = 8q + 4*grp; float4 epilogue.
template <bool LAST>
__global__ __launch_bounds__(256) void k_aggregate(
    const uint4* __restrict__ g4,
    const int2* __restrict__ rowinfo, const int* __restrict__ csr,
    const float* __restrict__ dinv, const float* __restrict__ bias,
    const float* __restrict__ Wo, const float* __restrict__ bo,
    float* __restrict__ outRow, float* __restrict__ outHead, int n) {
    int w = (blockIdx.x * blockDim.x + threadIdx.x) >> 6;
    int lane = threadIdx.x & 63;
    const int s = lane >> 4;                  // node slot 0..3
    const int grp = (lane >> 3) & 1;          // 0..1
    const int q = lane & 7;                   // 0..7
    int node = 4 * w + s;
    const bool valid = node < n;
    int2 ri = valid ? rowinfo[node] : make_int2(0, 0);
    const int e = ri.x;
    const int rnds = ri.y >> 1;
    int rm = rnds;
    rm = max(rm, __shfl_xor(rm, 16, 64));
    rm = max(rm, __shfl_xor(rm, 32, 64));     // max over 4 slots
    v2f a0v = {0.f, 0.f}, a1v = {0.f, 0.f}, a2v = {0.f, 0.f}, a3v = {0.f, 0.f};
    int r = 0;
    for (; r + 2 <= rm; r += 2) {             // 16 edge-rows in flight / wave
        int c0 = csr[e + 2 * r + grp];
        int c1 = csr[e + 2 * r + 2 + grp];
        int i0 = (r < rnds) ? c0 : n;
        int i1 = (r + 1 < rnds) ? c1 : n;
        uint4 x0 = g4[(size_t)i0 * 8 + q];
        uint4 x1 = g4[(size_t)i1 * 8 + q];
        a0v += bf2(x0.x); a1v += bf2(x0.y); a2v += bf2(x0.z); a3v += bf2(x0.w);
        a0v += bf2(x1.x); a1v += bf2(x1.y); a2v += bf2(x1.z); a3v += bf2(x1.w);
    }
    if (r < rm) {
        int c0 = csr[e + 2 * r + grp];
        int i0 = (r < rnds) ? c0 : n;
        uint4 x0 = g4[(size_t)i0 * 8 + q];
        a0v += bf2(x0.x); a1v += bf2(x0.y); a2v += bf2(x0.z); a3v += bf2(x0.w);
    }
    // one halving round over grp (mask 8): grp0 ends with feat 8q..8q+3,
    // grp1 with 8q+4..8q+7
    v2f keep0 = grp ? a2v : a0v;
    v2f keep1 = grp ? a3v : a1v;
    v2f send0 = grp ? a0v : a2v;
    v2f send1 = grp ? a1v : a3v;
    keep0.x += __shfl_xor(send0.x, 8, 64);
    keep0.y += __shfl_xor(send0.y, 8, 64);
    keep1.x += __shfl_xor(send1.x, 8, 64);
    keep1.y += __shfl_xor(send1.y, 8, 64);
    const int base = 8 * q + 4 * grp;
    float dv = valid ? dinv[node] : 0.f;
    float4 bb = *(const float4*)&bias[base];
    float4 vv;
    vv.x = fmaxf(fmaf(dv, keep0.x, bb.x), 0.f);
    vv.y = fmaxf(fmaf(dv, keep0.y, bb.y), 0.f);
    vv.z = fmaxf(fmaf(dv, keep1.x, bb.z), 0.f);
    vv.w = fmaxf(fmaf(dv, keep1.y, bb.w), 0.f);
    if constexpr (LAST) {
        float4 ww = *(const float4*)&Wo[base];
        float p = vv.x * ww.x + vv.y * ww.y + vv.z * ww.z + vv.w * ww.w;
#pragma unroll
        for (int m = 1; m <= 8; m <<= 1) p += __shfl_xor(p, m, 64);
        if ((lane & 15) == 0 && valid) outHead[node] = p + bo[0];
    } else {
        if (valid) *(float4*)&outRow[(size_t)node * 64 + base] = vv;
    }
}

extern "C" void kernel_launch(void* const* d_in, const int* in_sizes, int n_in,
                              void* d_out, int out_size, void* d_ws, size_t ws_size,
                              hipStream_t stream) {
    const float* x  = (const float*)d_in[0];
    const int*   ei = (const int*)d_in[1];
    const float* W1 = (const float*)d_in[2];
    const float* b1 = (const float*)d_in[3];
    const float* W2 = (const float*)d_in[4];
    const float* b2 = (const float*)d_in[5];
    const float* Wo = (const float*)d_in[6];
    const float* bo = (const float*)d_in[7];
    float* out = (float*)d_out;

    const int n = in_sizes[0] / 64;
    const int E = in_sizes[1] / 2;
    const int* src = ei;
    const int* dst = ei + E;

    const int nbuck = (n + BUCK_NODES - 1) >> NB_SHIFT;      // 391
    const int nchunks = (E + CHUNK - 1) / CHUNK;             // 306

    char* ws = (char*)d_ws;
    size_t off = 0;
    auto alloc = [&](size_t bytes) -> void* {
        void* p = ws + off;
        off += (bytes + 255) & ~(size_t)255;
        return p;
    };
    const size_t slabBytes = (size_t)nbuck * CAP * 4;        // 8.0 MB
    const size_t hBytes    = (size_t)n * 64 * 4;             // 25.6 MB (fp32 h1)
    const size_t gBytes    = (size_t)(n + 1) * 64 * 2;       // 12.8 MB (bf16 g + dummy)
    float*          dinv    = (float*)alloc((size_t)n * 4);
    int*            gcur    = (int*)alloc((size_t)nbuck * 4);
    int2*           rowinfo = (int2*)alloc((size_t)n * 8);
    int*            csr     = (int*)alloc(slabBytes);
    char*           regionA = (char*)alloc(hBytes > slabBytes ? hBytes : slabBytes);
    unsigned short* gBf     = (unsigned short*)alloc(gBytes);
    unsigned* packed = (unsigned*)regionA;   // dead after k_csr
    float*    bufH   = (float*)regionA;      // h1 (fp32), written from agg1 on

    // ---- init (slab cursors + dummy bf16 row) ----
    k_init<<<1, 512, 0, stream>>>(gcur, nbuck, gBf + (size_t)n * 64);

    // ---- slab counting sort -> dst-sorted csr slabs + rowinfo + dinv ----
    k_bsort<<<nchunks, STPB, 0, stream>>>(src, dst, E, nbuck, gcur, packed);
    k_csr<<<nbuck, 512, 0, stream>>>(packed, gcur, n, csr, rowinfo, dinv);

    const int gemmGrid = (n + 63) / 64;
    const int nodeGrid = (n + 15) / 16;      // 4 nodes/wave, 4 waves/block

    // ---- layer 1 ----
    k_gemm64bf<<<gemmGrid, 256, 0, stream>>>(x, W1, dinv, gBf, n);
    k_aggregate<false><<<nodeGrid, 256, 0, stream>>>((const uint4*)gBf, rowinfo, csr,
                                                     dinv, b1, nullptr, nullptr,
                                                     bufH, nullptr, n);
    // ---- layer 2 (head fused into epilogue) ----
    k_gemm64bf<<<gemmGrid, 256, 0, stream>>>(bufH, W2, dinv, gBf, n);
    k_aggregate<true><<<nodeGrid, 256, 0, stream>>>((const uint4*)gBf, rowinfo, csr,
                                                    dinv, b2, Wo, bo,
                                                    nullptr, out, n);
}

// Round 15
// 140.390 us; speedup vs baseline: 1.1301x; 1.1301x over previous
//
#include <hip/hip_runtime.h>

// GCN 2-layer + linear head on MI355X.
// R14 post-mortem: reverting the s_load GEMM cost +18us (140.4->158.7) --
// R13's "46us gemm" profile entry was a cold-dispatch artifact; the timed
// graph says the readfirstlane/s_load GEMM is ~9us/GEMM FASTER (1 VALU/FMA,
// SMEM latency hidden by TLP). R15: restore R13 exactly.

typedef float v2f __attribute__((ext_vector_type(2)));

constexpr int NB_SHIFT = 8;                 // 256 nodes per bucket
constexpr int BUCK_NODES = 1 << NB_SHIFT;
constexpr int CAP = 5120;                   // slab cap (max bucket ~3500 + 512 self + pad)
constexpr int CHUNK = 4096;                 // edges per sort block
constexpr int STPB = 512;
// assumes nbuck <= 512, src < 2^17, padded bucket size <= CAP

// ---- init: slab cursors + dummy bf16 row (replaces hipMemsetAsync) -----
__global__ __launch_bounds__(512) void k_init(int* __restrict__ gcur, int nbuck,
                                              unsigned short* __restrict__ dummyRow) {
    int t = threadIdx.x;
    if (t < nbuck) gcur[t] = 0;
    if (t < 64) dummyRow[t] = 0;
}

// ---- fused: chunk histogram -> slab reserve -> LDS sort -> dense flush -
__global__ __launch_bounds__(STPB) void k_bsort(const int* __restrict__ src,
                                                const int* __restrict__ dst, int E, int nbuck,
                                                int* __restrict__ gcur,
                                                unsigned* __restrict__ packed) {
    __shared__ int shStart[512];
    __shared__ int shCur[512];
    __shared__ int shOff[512];
    __shared__ unsigned stage[CHUNK];
    __shared__ unsigned short sbkt[CHUNK];
    const int tid = threadIdx.x;
    const int base = blockIdx.x * CHUNK;
    const int end = min(base + CHUNK, E);
    // pass A: count buckets in this chunk (LDS atomics)
    shCur[tid] = 0;
    __syncthreads();
    for (int e = base + tid; e < end; e += STPB)
        atomicAdd(&shCur[dst[e] >> NB_SHIFT], 1);
    __syncthreads();
    int v = shCur[tid];
    shStart[tid] = v;
    __syncthreads();
    for (int s = 1; s < 512; s <<= 1) {      // inclusive Hillis-Steele
        int a = (tid >= s) ? shStart[tid - s] : 0;
        __syncthreads();
        shStart[tid] += a;
        __syncthreads();
    }
    int exc = shStart[tid] - v;
    shStart[tid] = exc;
    shCur[tid] = exc;
    // reserve this chunk's span in bucket slabs (one global atomic each)
    if (tid < nbuck) shOff[tid] = tid * CAP + ((v > 0) ? atomicAdd(&gcur[tid], v) : 0);
    __syncthreads();
    // pass B: permute chunk into LDS, bucket-major
    for (int e = base + tid; e < end; e += STPB) {
        int s = src[e];
        int d = dst[e];
        int b = d >> NB_SHIFT;
        int slot = atomicAdd(&shCur[b], 1);
        stage[slot] = ((unsigned)(d & (BUCK_NODES - 1)) << 17) | (unsigned)s;
        sbkt[slot] = (unsigned short)b;
    }
    __syncthreads();
    // pass C: linear flush, same-bucket runs land contiguously
    int cnt = end - base;
    for (int i = tid; i < cnt; i += STPB) {
        int b = sbkt[i];
        packed[shOff[b] + (i - shStart[b])] = stage[i];
    }
}

// ---- per-bucket counting sort by dstLocal -> csr slab; appends SELF edge
//      then pads to x2. rowinfo=(start, paddedCount), dinv ---------------
__global__ __launch_bounds__(512) void k_csr(const unsigned* __restrict__ packed,
                                             const int* __restrict__ gcur, int n,
                                             int* __restrict__ csr, int2* __restrict__ rowinfo,
                                             float* __restrict__ dinv) {
    __shared__ int cnt[BUCK_NODES];
    __shared__ int scn[BUCK_NODES];
    __shared__ int cur[BUCK_NODES];
    const int tid = threadIdx.x;
    const int e0 = blockIdx.x * CAP;
    const int e1 = e0 + gcur[blockIdx.x];     // slab base + size
    if (tid < BUCK_NODES) cnt[tid] = 0;
    __syncthreads();
    for (int e = e0 + tid; e < e1; e += 512)
        atomicAdd(&cnt[packed[e] >> 17], 1);
    __syncthreads();
    int v = (tid < BUCK_NODES) ? cnt[tid] : 0;
    int pad = (v + 2) & ~1;                   // v edges + 1 self, rounded to x2
    if (tid < BUCK_NODES) scn[tid] = pad;
    __syncthreads();
    for (int s = 1; s < BUCK_NODES; s <<= 1) {   // inclusive Hillis-Steele
        int add = (tid >= s && tid < BUCK_NODES) ? scn[tid - s] : 0;
        __syncthreads();
        if (tid < BUCK_NODES) scn[tid] += add;
        __syncthreads();
    }
    int start = 0;
    if (tid < BUCK_NODES) {
        start = e0 + scn[tid] - pad;
        cur[tid] = start;
        int node = blockIdx.x * BUCK_NODES + tid;
        if (node < n) {
            rowinfo[node] = make_int2(start, pad);
            dinv[node] = rsqrtf(1.0f + (float)v);
        }
    }
    __syncthreads();
    for (int e = e0 + tid; e < e1; e += 512) {
        unsigned p = packed[e];
        int pos = atomicAdd(&cur[p >> 17], 1);   // LDS cursor
        csr[pos] = (int)(p & 0x1FFFFu);          // dense slab window, L2-hot
    }
    __syncthreads();
    // append self edge, then dummy-pad (index n = zero bf16 row)
    if (tid < BUCK_NODES) {
        int node = blockIdx.x * BUCK_NODES + tid;
        csr[start + v] = (node < n) ? node : n;
        for (int p = v + 1; p < pad; ++p) csr[start + p] = n;
    }
}

// ---- GEMM: gBf[i][f] = bf16((sum_k A[i][k] * W[k][f]) * dinv[i]) -------
// A-row pointer forced to SGPR via readfirstlane -> scalar s_loads,
// v_fmac v,s,v = 1 VALU instr per FMA. (Timed-graph verified faster than
// the readlane form: R13 140.4us vs R14 158.7us, only this differing.)
__global__ __launch_bounds__(256) void k_gemm64bf(const float* __restrict__ A,
                                                  const float* __restrict__ W,
                                                  const float* __restrict__ dinv,
                                                  unsigned short* __restrict__ out,
                                                  int n) {
    const int lane = threadIdx.x & 63;
    const int wave = threadIdx.x >> 6;
    float wcol[64];
#pragma unroll
    for (int k = 0; k < 64; ++k) wcol[k] = W[k * 64 + lane];
    int base = blockIdx.x * 64;
    for (int r = wave; r < 64; r += 4) {
        int row = base + r;
        if (row >= n) break;
        int urow = __builtin_amdgcn_readfirstlane(row);   // SGPR row index
        const float* Ar = A + (size_t)urow * 64;          // uniform -> s_load path
        float acc = 0.0f;
#pragma unroll
        for (int k = 0; k < 64; ++k) acc = fmaf(Ar[k], wcol[k], acc);
        float val = acc * dinv[urow];
        unsigned u = __float_as_uint(val);
        u = (u + 0x7FFFu + ((u >> 16) & 1u)) >> 16;   // RNE to bf16
        out[(size_t)urow * 64 + lane] = (unsigned short)u;
    }
}

__device__ __forceinline__ v2f bf2(unsigned u) {
    v2f r;
    r.x = __uint_as_float(u << 16);
    r.y = __uint_as_float(u & 0xFFFF0000u);
    return r;
}

// ---- Aggregate: FOUR nodes per wave (16 lanes each); bf16 rows ---------
// lane = 16*s + 8*grp + q. Node slot s; grp in {0,1} handles edge e+2r+grp;
// q the 16B row chunk (features 8q..8q+7). Self-loop is already in csr.
// Reduce: 1 halving round (mask 8) -> each lane owns 4 features
// base = 8q + 4*grp; float4 epilogue.
template <bool LAST>
__global__ __launch_bounds__(256) void k_aggregate(
    const uint4* __restrict__ g4,
    const int2* __restrict__ rowinfo, const int* __restrict__ csr,
    const float* __restrict__ dinv, const float* __restrict__ bias,
    const float* __restrict__ Wo, const float* __restrict__ bo,
    float* __restrict__ outRow, float* __restrict__ outHead, int n) {
    int w = (blockIdx.x * blockDim.x + threadIdx.x) >> 6;
    int lane = threadIdx.x & 63;
    const int s = lane >> 4;                  // node slot 0..3
    const int grp = (lane >> 3) & 1;          // 0..1
    const int q = lane & 7;                   // 0..7
    int node = 4 * w + s;
    const bool valid = node < n;
    int2 ri = valid ? rowinfo[node] : make_int2(0, 0);
    const int e = ri.x;
    const int rnds = ri.y >> 1;
    int rm = rnds;
    rm = max(rm, __shfl_xor(rm, 16, 64));
    rm = max(rm, __shfl_xor(rm, 32, 64));     // max over 4 slots
    v2f a0v = {0.f, 0.f}, a1v = {0.f, 0.f}, a2v = {0.f, 0.f}, a3v = {0.f, 0.f};
    int r = 0;
    for (; r + 2 <= rm; r += 2) {             // 16 edge-rows in flight / wave
        int c0 = csr[e + 2 * r + grp];
        int c1 = csr[e + 2 * r + 2 + grp];
        int i0 = (r < rnds) ? c0 : n;
        int i1 = (r + 1 < rnds) ? c1 : n;
        uint4 x0 = g4[(size_t)i0 * 8 + q];
        uint4 x1 = g4[(size_t)i1 * 8 + q];
        a0v += bf2(x0.x); a1v += bf2(x0.y); a2v += bf2(x0.z); a3v += bf2(x0.w);
        a0v += bf2(x1.x); a1v += bf2(x1.y); a2v += bf2(x1.z); a3v += bf2(x1.w);
    }
    if (r < rm) {
        int c0 = csr[e + 2 * r + grp];
        int i0 = (r < rnds) ? c0 : n;
        uint4 x0 = g4[(size_t)i0 * 8 + q];
        a0v += bf2(x0.x); a1v += bf2(x0.y); a2v += bf2(x0.z); a3v += bf2(x0.w);
    }
    // one halving round over grp (mask 8): grp0 ends with feat 8q..8q+3,
    // grp1 with 8q+4..8q+7
    v2f keep0 = grp ? a2v : a0v;
    v2f keep1 = grp ? a3v : a1v;
    v2f send0 = grp ? a0v : a2v;
    v2f send1 = grp ? a1v : a3v;
    keep0.x += __shfl_xor(send0.x, 8, 64);
    keep0.y += __shfl_xor(send0.y, 8, 64);
    keep1.x += __shfl_xor(send1.x, 8, 64);
    keep1.y += __shfl_xor(send1.y, 8, 64);
    const int base = 8 * q + 4 * grp;
    float dv = valid ? dinv[node] : 0.f;
    float4 bb = *(const float4*)&bias[base];
    float4 vv;
    vv.x = fmaxf(fmaf(dv, keep0.x, bb.x), 0.f);
    vv.y = fmaxf(fmaf(dv, keep0.y, bb.y), 0.f);
    vv.z = fmaxf(fmaf(dv, keep1.x, bb.z), 0.f);
    vv.w = fmaxf(fmaf(dv, keep1.y, bb.w), 0.f);
    if constexpr (LAST) {
        float4 ww = *(const float4*)&Wo[base];
        float p = vv.x * ww.x + vv.y * ww.y + vv.z * ww.z + vv.w * ww.w;
#pragma unroll
        for (int m = 1; m <= 8; m <<= 1) p += __shfl_xor(p, m, 64);
        if ((lane & 15) == 0 && valid) outHead[node] = p + bo[0];
    } else {
        if (valid) *(float4*)&outRow[(size_t)node * 64 + base] = vv;
    }
}

extern "C" void kernel_launch(void* const* d_in, const int* in_sizes, int n_in,
                              void* d_out, int out_size, void* d_ws, size_t ws_size,
                              hipStream_t stream) {
    const float* x  = (const float*)d_in[0];
    const int*   ei = (const int*)d_in[1];
    const float* W1 = (const float*)d_in[2];
    const float* b1 = (const float*)d_in[3];
    const float* W2 = (const float*)d_in[4];
    const float* b2 = (const float*)d_in[5];
    const float* Wo = (const float*)d_in[6];
    const float* bo = (const float*)d_in[7];
    float* out = (float*)d_out;

    const int n = in_sizes[0] / 64;
    const int E = in_sizes[1] / 2;
    const int* src = ei;
    const int* dst = ei + E;

    const int nbuck = (n + BUCK_NODES - 1) >> NB_SHIFT;      // 391
    const int nchunks = (E + CHUNK - 1) / CHUNK;             // 306

    char* ws = (char*)d_ws;
    size_t off = 0;
    auto alloc = [&](size_t bytes) -> void* {
        void* p = ws + off;
        off += (bytes + 255) & ~(size_t)255;
        return p;
    };
    const size_t slabBytes = (size_t)nbuck * CAP * 4;        // 8.0 MB
    const size_t hBytes    = (size_t)n * 64 * 4;             // 25.6 MB (fp32 h1)
    const size_t gBytes    = (size_t)(n + 1) * 64 * 2;       // 12.8 MB (bf16 g + dummy)
    float*          dinv    = (float*)alloc((size_t)n * 4);
    int*            gcur    = (int*)alloc((size_t)nbuck * 4);
    int2*           rowinfo = (int2*)alloc((size_t)n * 8);
    int*            csr     = (int*)alloc(slabBytes);
    char*           regionA = (char*)alloc(hBytes > slabBytes ? hBytes : slabBytes);
    unsigned short* gBf     = (unsigned short*)alloc(gBytes);
    unsigned* packed = (unsigned*)regionA;   // dead after k_csr
    float*    bufH   = (float*)regionA;      // h1 (fp32), written from agg1 on

    // ---- init (slab cursors + dummy bf16 row) ----
    k_init<<<1, 512, 0, stream>>>(gcur, nbuck, gBf + (size_t)n * 64);

    // ---- slab counting sort -> dst-sorted csr slabs + rowinfo + dinv ----
    k_bsort<<<nchunks, STPB, 0, stream>>>(src, dst, E, nbuck, gcur, packed);
    k_csr<<<nbuck, 512, 0, stream>>>(packed, gcur, n, csr, rowinfo, dinv);

    const int gemmGrid = (n + 63) / 64;
    const int nodeGrid = (n + 15) / 16;      // 4 nodes/wave, 4 waves/block

    // ---- layer 1 ----
    k_gemm64bf<<<gemmGrid, 256, 0, stream>>>(x, W1, dinv, gBf, n);
    k_aggregate<false><<<nodeGrid, 256, 0, stream>>>((const uint4*)gBf, rowinfo, csr,
                                                     dinv, b1, nullptr, nullptr,
                                                     bufH, nullptr, n);
    // ---- layer 2 (head fused into epilogue) ----
    k_gemm64bf<<<gemmGrid, 256, 0, stream>>>(bufH, W2, dinv, gBf, n);
    k_aggregate<true><<<nodeGrid, 256, 0, stream>>>((const uint4*)gBf, rowinfo, csr,
                                                    dinv, b2, Wo, bo,
                                                    nullptr, out, n);
}

// Round 16
// 136.222 us; speedup vs baseline: 1.1647x; 1.0306x over previous
//
#include <hip/hip_runtime.h>

// GCN 2-layer + linear head on MI355X.
// R15 post-mortem: 140.4us state restored (s_load GEMM verified by timed
// A/B/A; rocprof per-dispatch times for it are replay artifacts).
// R16: agg gather loop unrolled 4-deep -- 4 independent row gathers in
// flight per wave (was 2; ~5.6KB/CU outstanding was exactly at the
// latency-BW edge). Everything else identical to R15.

typedef float v2f __attribute__((ext_vector_type(2)));

constexpr int NB_SHIFT = 8;                 // 256 nodes per bucket
constexpr int BUCK_NODES = 1 << NB_SHIFT;
constexpr int CAP = 5120;                   // slab cap (max bucket ~3500 + 512 self + pad)
constexpr int CHUNK = 4096;                 // edges per sort block
constexpr int STPB = 512;
// assumes nbuck <= 512, src < 2^17, padded bucket size <= CAP

// ---- init: slab cursors + dummy bf16 row (replaces hipMemsetAsync) -----
__global__ __launch_bounds__(512) void k_init(int* __restrict__ gcur, int nbuck,
                                              unsigned short* __restrict__ dummyRow) {
    int t = threadIdx.x;
    if (t < nbuck) gcur[t] = 0;
    if (t < 64) dummyRow[t] = 0;
}

// ---- fused: chunk histogram -> slab reserve -> LDS sort -> dense flush -
__global__ __launch_bounds__(STPB) void k_bsort(const int* __restrict__ src,
                                                const int* __restrict__ dst, int E, int nbuck,
                                                int* __restrict__ gcur,
                                                unsigned* __restrict__ packed) {
    __shared__ int shStart[512];
    __shared__ int shCur[512];
    __shared__ int shOff[512];
    __shared__ unsigned stage[CHUNK];
    __shared__ unsigned short sbkt[CHUNK];
    const int tid = threadIdx.x;
    const int base = blockIdx.x * CHUNK;
    const int end = min(base + CHUNK, E);
    // pass A: count buckets in this chunk (LDS atomics)
    shCur[tid] = 0;
    __syncthreads();
    for (int e = base + tid; e < end; e += STPB)
        atomicAdd(&shCur[dst[e] >> NB_SHIFT], 1);
    __syncthreads();
    int v = shCur[tid];
    shStart[tid] = v;
    __syncthreads();
    for (int s = 1; s < 512; s <<= 1) {      // inclusive Hillis-Steele
        int a = (tid >= s) ? shStart[tid - s] : 0;
        __syncthreads();
        shStart[tid] += a;
        __syncthreads();
    }
    int exc = shStart[tid] - v;
    shStart[tid] = exc;
    shCur[tid] = exc;
    // reserve this chunk's span in bucket slabs (one global atomic each)
    if (tid < nbuck) shOff[tid] = tid * CAP + ((v > 0) ? atomicAdd(&gcur[tid], v) : 0);
    __syncthreads();
    // pass B: permute chunk into LDS, bucket-major
    for (int e = base + tid; e < end; e += STPB) {
        int s = src[e];
        int d = dst[e];
        int b = d >> NB_SHIFT;
        int slot = atomicAdd(&shCur[b], 1);
        stage[slot] = ((unsigned)(d & (BUCK_NODES - 1)) << 17) | (unsigned)s;
        sbkt[slot] = (unsigned short)b;
    }
    __syncthreads();
    // pass C: linear flush, same-bucket runs land contiguously
    int cnt = end - base;
    for (int i = tid; i < cnt; i += STPB) {
        int b = sbkt[i];
        packed[shOff[b] + (i - shStart[b])] = stage[i];
    }
}

// ---- per-bucket counting sort by dstLocal -> csr slab; appends SELF edge
//      then pads to x2. rowinfo=(start, paddedCount), dinv ---------------
__global__ __launch_bounds__(512) void k_csr(const unsigned* __restrict__ packed,
                                             const int* __restrict__ gcur, int n,
                                             int* __restrict__ csr, int2* __restrict__ rowinfo,
                                             float* __restrict__ dinv) {
    __shared__ int cnt[BUCK_NODES];
    __shared__ int scn[BUCK_NODES];
    __shared__ int cur[BUCK_NODES];
    const int tid = threadIdx.x;
    const int e0 = blockIdx.x * CAP;
    const int e1 = e0 + gcur[blockIdx.x];     // slab base + size
    if (tid < BUCK_NODES) cnt[tid] = 0;
    __syncthreads();
    for (int e = e0 + tid; e < e1; e += 512)
        atomicAdd(&cnt[packed[e] >> 17], 1);
    __syncthreads();
    int v = (tid < BUCK_NODES) ? cnt[tid] : 0;
    int pad = (v + 2) & ~1;                   // v edges + 1 self, rounded to x2
    if (tid < BUCK_NODES) scn[tid] = pad;
    __syncthreads();
    for (int s = 1; s < BUCK_NODES; s <<= 1) {   // inclusive Hillis-Steele
        int add = (tid >= s && tid < BUCK_NODES) ? scn[tid - s] : 0;
        __syncthreads();
        if (tid < BUCK_NODES) scn[tid] += add;
        __syncthreads();
    }
    int start = 0;
    if (tid < BUCK_NODES) {
        start = e0 + scn[tid] - pad;
        cur[tid] = start;
        int node = blockIdx.x * BUCK_NODES + tid;
        if (node < n) {
            rowinfo[node] = make_int2(start, pad);
            dinv[node] = rsqrtf(1.0f + (float)v);
        }
    }
    __syncthreads();
    for (int e = e0 + tid; e < e1; e += 512) {
        unsigned p = packed[e];
        int pos = atomicAdd(&cur[p >> 17], 1);   // LDS cursor
        csr[pos] = (int)(p & 0x1FFFFu);          // dense slab window, L2-hot
    }
    __syncthreads();
    // append self edge, then dummy-pad (index n = zero bf16 row)
    if (tid < BUCK_NODES) {
        int node = blockIdx.x * BUCK_NODES + tid;
        csr[start + v] = (node < n) ? node : n;
        for (int p = v + 1; p < pad; ++p) csr[start + p] = n;
    }
}

// ---- GEMM: gBf[i][f] = bf16((sum_k A[i][k] * W[k][f]) * dinv[i]) -------
// A-row pointer forced to SGPR via readfirstlane -> scalar s_loads,
// v_fmac v,s,v = 1 VALU instr per FMA. (Timed-graph verified: R13/R14/R15.)
__global__ __launch_bounds__(256) void k_gemm64bf(const float* __restrict__ A,
                                                  const float* __restrict__ W,
                                                  const float* __restrict__ dinv,
                                                  unsigned short* __restrict__ out,
                                                  int n) {
    const int lane = threadIdx.x & 63;
    const int wave = threadIdx.x >> 6;
    float wcol[64];
#pragma unroll
    for (int k = 0; k < 64; ++k) wcol[k] = W[k * 64 + lane];
    int base = blockIdx.x * 64;
    for (int r = wave; r < 64; r += 4) {
        int row = base + r;
        if (row >= n) break;
        int urow = __builtin_amdgcn_readfirstlane(row);   // SGPR row index
        const float* Ar = A + (size_t)urow * 64;          // uniform -> s_load path
        float acc = 0.0f;
#pragma unroll
        for (int k = 0; k < 64; ++k) acc = fmaf(Ar[k], wcol[k], acc);
        float val = acc * dinv[urow];
        unsigned u = __float_as_uint(val);
        u = (u + 0x7FFFu + ((u >> 16) & 1u)) >> 16;   // RNE to bf16
        out[(size_t)urow * 64 + lane] = (unsigned short)u;
    }
}

__device__ __forceinline__ v2f bf2(unsigned u) {
    v2f r;
    r.x = __uint_as_float(u << 16);
    r.y = __uint_as_float(u & 0xFFFF0000u);
    return r;
}

// ---- Aggregate: FOUR nodes per wave (16 lanes each); bf16 rows ---------
// lane = 16*s + 8*grp + q. Node slot s; grp in {0,1} handles edge e+2r+grp;
// q the 16B row chunk (features 8q..8q+7). Self-loop is already in csr.
// R16: 4-deep gather unroll (4 independent loads in flight).
// Reduce: 1 halving round (mask 8) -> each lane owns 4 features
// base = 8q + 4*grp; float4 epilogue.
template <bool LAST>
__global__ __launch_bounds__(256) void k_aggregate(
    const uint4* __restrict__ g4,
    const int2* __restrict__ rowinfo, const int* __restrict__ csr,
    const float* __restrict__ dinv, const float* __restrict__ bias,
    const float* __restrict__ Wo, const float* __restrict__ bo,
    float* __restrict__ outRow, float* __restrict__ outHead, int n) {
    int w = (blockIdx.x * blockDim.x + threadIdx.x) >> 6;
    int lane = threadIdx.x & 63;
    const int s = lane >> 4;                  // node slot 0..3
    const int grp = (lane >> 3) & 1;          // 0..1
    const int q = lane & 7;                   // 0..7
    int node = 4 * w + s;
    const bool valid = node < n;
    int2 ri = valid ? rowinfo[node] : make_int2(0, 0);
    const int e = ri.x;
    const int rnds = ri.y >> 1;
    int rm = rnds;
    rm = max(rm, __shfl_xor(rm, 16, 64));
    rm = max(rm, __shfl_xor(rm, 32, 64));     // max over 4 slots
    v2f a0v = {0.f, 0.f}, a1v = {0.f, 0.f}, a2v = {0.f, 0.f}, a3v = {0.f, 0.f};
    int r = 0;
    for (; r + 4 <= rm; r += 4) {             // 32 edge-rows in flight / wave
        int c0 = csr[e + 2 * r + grp];        // shared base + imm offsets
        int c1 = csr[e + 2 * r + 2 + grp];
        int c2 = csr[e + 2 * r + 4 + grp];
        int c3 = csr[e + 2 * r + 6 + grp];
        int i0 = (r < rnds) ? c0 : n;
        int i1 = (r + 1 < rnds) ? c1 : n;
        int i2 = (r + 2 < rnds) ? c2 : n;
        int i3 = (r + 3 < rnds) ? c3 : n;
        uint4 x0 = g4[(size_t)i0 * 8 + q];
        uint4 x1 = g4[(size_t)i1 * 8 + q];
        uint4 x2 = g4[(size_t)i2 * 8 + q];
        uint4 x3 = g4[(size_t)i3 * 8 + q];
        a0v += bf2(x0.x); a1v += bf2(x0.y); a2v += bf2(x0.z); a3v += bf2(x0.w);
        a0v += bf2(x1.x); a1v += bf2(x1.y); a2v += bf2(x1.z); a3v += bf2(x1.w);
        a0v += bf2(x2.x); a1v += bf2(x2.y); a2v += bf2(x2.z); a3v += bf2(x2.w);
        a0v += bf2(x3.x); a1v += bf2(x3.y); a2v += bf2(x3.z); a3v += bf2(x3.w);
    }
    for (; r < rm; ++r) {                     // tail (<=3 rounds)
        int c0 = csr[e + 2 * r + grp];
        int i0 = (r < rnds) ? c0 : n;
        uint4 x0 = g4[(size_t)i0 * 8 + q];
        a0v += bf2(x0.x); a1v += bf2(x0.y); a2v += bf2(x0.z); a3v += bf2(x0.w);
    }
    // one halving round over grp (mask 8): grp0 ends with feat 8q..8q+3,
    // grp1 with 8q+4..8q+7
    v2f keep0 = grp ? a2v : a0v;
    v2f keep1 = grp ? a3v : a1v;
    v2f send0 = grp ? a0v : a2v;
    v2f send1 = grp ? a1v : a3v;
    keep0.x += __shfl_xor(send0.x, 8, 64);
    keep0.y += __shfl_xor(send0.y, 8, 64);
    keep1.x += __shfl_xor(send1.x, 8, 64);
    keep1.y += __shfl_xor(send1.y, 8, 64);
    const int base = 8 * q + 4 * grp;
    float dv = valid ? dinv[node] : 0.f;
    float4 bb = *(const float4*)&bias[base];
    float4 vv;
    vv.x = fmaxf(fmaf(dv, keep0.x, bb.x), 0.f);
    vv.y = fmaxf(fmaf(dv, keep0.y, bb.y), 0.f);
    vv.z = fmaxf(fmaf(dv, keep1.x, bb.z), 0.f);
    vv.w = fmaxf(fmaf(dv, keep1.y, bb.w), 0.f);
    if constexpr (LAST) {
        float4 ww = *(const float4*)&Wo[base];
        float p = vv.x * ww.x + vv.y * ww.y + vv.z * ww.z + vv.w * ww.w;
#pragma unroll
        for (int m = 1; m <= 8; m <<= 1) p += __shfl_xor(p, m, 64);
        if ((lane & 15) == 0 && valid) outHead[node] = p + bo[0];
    } else {
        if (valid) *(float4*)&outRow[(size_t)node * 64 + base] = vv;
    }
}

extern "C" void kernel_launch(void* const* d_in, const int* in_sizes, int n_in,
                              void* d_out, int out_size, void* d_ws, size_t ws_size,
                              hipStream_t stream) {
    const float* x  = (const float*)d_in[0];
    const int*   ei = (const int*)d_in[1];
    const float* W1 = (const float*)d_in[2];
    const float* b1 = (const float*)d_in[3];
    const float* W2 = (const float*)d_in[4];
    const float* b2 = (const float*)d_in[5];
    const float* Wo = (const float*)d_in[6];
    const float* bo = (const float*)d_in[7];
    float* out = (float*)d_out;

    const int n = in_sizes[0] / 64;
    const int E = in_sizes[1] / 2;
    const int* src = ei;
    const int* dst = ei + E;

    const int nbuck = (n + BUCK_NODES - 1) >> NB_SHIFT;      // 391
    const int nchunks = (E + CHUNK - 1) / CHUNK;             // 306

    char* ws = (char*)d_ws;
    size_t off = 0;
    auto alloc = [&](size_t bytes) -> void* {
        void* p = ws + off;
        off += (bytes + 255) & ~(size_t)255;
        return p;
    };
    const size_t slabBytes = (size_t)nbuck * CAP * 4 + 4096; // 8.0 MB (+over-read slack)
    const size_t hBytes    = (size_t)n * 64 * 4;             // 25.6 MB (fp32 h1)
    const size_t gBytes    = (size_t)(n + 1) * 64 * 2;       // 12.8 MB (bf16 g + dummy)
    float*          dinv    = (float*)alloc((size_t)n * 4);
    int*            gcur    = (int*)alloc((size_t)nbuck * 4);
    int2*           rowinfo = (int2*)alloc((size_t)n * 8);
    int*            csr     = (int*)alloc(slabBytes);
    char*           regionA = (char*)alloc(hBytes > slabBytes ? hBytes : slabBytes);
    unsigned short* gBf     = (unsigned short*)alloc(gBytes);
    unsigned* packed = (unsigned*)regionA;   // dead after k_csr
    float*    bufH   = (float*)regionA;      // h1 (fp32), written from agg1 on

    // ---- init (slab cursors + dummy bf16 row) ----
    k_init<<<1, 512, 0, stream>>>(gcur, nbuck, gBf + (size_t)n * 64);

    // ---- slab counting sort -> dst-sorted csr slabs + rowinfo + dinv ----
    k_bsort<<<nchunks, STPB, 0, stream>>>(src, dst, E, nbuck, gcur, packed);
    k_csr<<<nbuck, 512, 0, stream>>>(packed, gcur, n, csr, rowinfo, dinv);

    const int gemmGrid = (n + 63) / 64;
    const int nodeGrid = (n + 15) / 16;      // 4 nodes/wave, 4 waves/block

    // ---- layer 1 ----
    k_gemm64bf<<<gemmGrid, 256, 0, stream>>>(x, W1, dinv, gBf, n);
    k_aggregate<false><<<nodeGrid, 256, 0, stream>>>((const uint4*)gBf, rowinfo, csr,
                                                     dinv, b1, nullptr, nullptr,
                                                     bufH, nullptr, n);
    // ---- layer 2 (head fused into epilogue) ----
    k_gemm64bf<<<gemmGrid, 256, 0, stream>>>(bufH, W2, dinv, gBf, n);
    k_aggregate<true><<<nodeGrid, 256, 0, stream>>>((const uint4*)gBf, rowinfo, csr,
                                                    dinv, b2, Wo, bo,
                                                    nullptr, out, n);
}